// Round 5
// baseline (17.119 us; speedup 1.0000x reference)
//
#include <hip/hip_runtime.h>

// Problem constants (from reference)
#define B_    2
#define H1_   64
#define W1_   96
#define H2_   64
#define W2_   96
#define HW_   (H1_ * W1_)          // 6144, also H2*W2
#define KWIN  81                   // 9x9 lookup window
#define CORR_ELEMS (B_ * KWIN * HW_)              // 995328
#define UP_HW      (8 * H1_ * 8 * W1_)            // 512*768

#define CORR_PIX    (B_ * HW_)                    // 12288 pixels
#define CORR_BLOCKS (CORR_PIX / 32)               // 384 blocks, 32 pixels each
#define UP_THREADS  (B_ * H1_ * 8 * 2 * W1_)      // 196608 (n,h,r,shalf,w); 4 s each
#define UP_BLOCKS   (UP_THREADS / 256)            // 768
#define TOT_BLOCKS  (CORR_BLOCKS + UP_BLOCKS)     // 1152, interleaved 1 corr : 2 up

#define PSTRIDE 101                               // LDS stride per pixel (101%32=5, coprime)

// ---------------------------------------------------------------------------
// Fused kernel, 256-thread blocks, roles interleaved by blockIdx%3:
//   role 0 (384 blocks): corr — 32 pixels/block, LDS-staged two-phase
//   role 1,2 (768 blocks): convex upsample — thread per (n,h,r,shalf,w), 4 s
// ---------------------------------------------------------------------------
__global__ __launch_bounds__(256) void fused_kernel(const float* __restrict__ cost,
                                                    const float* __restrict__ coords,
                                                    const float* __restrict__ flow,
                                                    const float* __restrict__ mask,
                                                    float* __restrict__ out) {
    __shared__ float patch[32 * PSTRIDE];          // 12.9 KB
    __shared__ int   xi0s[32];
    __shared__ int   yi0s[32];

    int role = blockIdx.x % 3;
    if (role == 0) {
        // ---------------- corr ----------------
        int cid  = blockIdx.x / 3;                  // [0, 384)
        int tid  = threadIdx.x;
        int px   = tid & 31;                        // pixel within block
        int m    = cid * 32 + px;                   // global pixel id
        int b    = m / HW_;                         // uniform per block
        int rem  = m - b * HW_;

        // phase 0: per-pixel params (each thread for its px; dup across groups)
        float cx = coords[b * 2 * HW_ + rem];
        float cy = coords[b * 2 * HW_ + HW_ + rem];
        float xf = floorf(cx), yf = floorf(cy);
        float wx = cx - xf,   wy = cy - yf;
        int xi0 = (int)xf - 4;
        int yi0 = (int)yf - 4;
        float w00 = (1.0f - wx) * (1.0f - wy);
        float w10 = wx * (1.0f - wy);
        float w01 = (1.0f - wx) * wy;
        float w11 = wx * wy;

        if (tid < 32) { xi0s[tid] = xi0; yi0s[tid] = yi0; }
        __syncthreads();

        // phase 1: cooperative patch load — 32 px * 100 elems = 3200 = 12.5*256
        const float* __restrict__ cmB = cost + (size_t)(cid * 32) * HW_;
#pragma unroll
        for (int it = 0; it < 13; ++it) {
            int l = it * 256 + tid;
            if (l < 3200) {
                unsigned pl = (unsigned)l / 100u;
                unsigned e  = (unsigned)l - pl * 100u;
                unsigned r  = e / 10u;
                unsigned c  = e - r * 10u;
                int y = yi0s[pl] + (int)r;
                int x = xi0s[pl] + (int)c;
                bool ok = (x >= 0) & (x < W2_) & (y >= 0) & (y < H2_);
                int yc = min(max(y, 0), H2_ - 1);
                int xc = min(max(x, 0), W2_ - 1);
                float v = cmB[pl * HW_ + yc * W2_ + xc];
                patch[pl * PSTRIDE + e] = ok ? v : 0.0f;
            }
        }
        __syncthreads();

        // phase 2: thread (px, g=tid>>5) computes channels g, g+8, g+16, ...
        const float* __restrict__ pp = patch + px * PSTRIDE;
        size_t obase = (size_t)b * KWIN * HW_ + rem;
        int g = tid >> 5;                            // 0..7
#pragma unroll
        for (int t = 0; t < 11; ++t) {
            int ch = g + 8 * t;
            if (ch < KWIN) {
                int p = ch / 9;
                int q = ch - p * 9;
                int o = q * 10 + p;
                float val = w00 * pp[o]      + w10 * pp[o + 1]
                          + w01 * pp[o + 10] + w11 * pp[o + 11];
                out[obase + (size_t)ch * HW_] = val; // 2x128B dense per wave
            }
        }
    } else {
        // ---------------- convex upsample ----------------
        int uid = blockIdx.x - blockIdx.x / 3 - 1;   // [0, 768) bijective
        int t = uid * 256 + threadIdx.x;             // [0, 196608)
        int w  = t % W1_;
        int t2 = t / W1_;
        int sh = t2 & 1;                             // s-half: s = sh*4 + j
        int t3 = t2 >> 1;
        int r  = t3 & 7;
        int t4 = t3 >> 3;
        int h  = t4 & 63;
        int n  = t4 >> 6;

        // mask: [B, 576, H1, W1]; channel = k*64 + r*8 + sh*4 + j
        const float* __restrict__ mp =
            mask + ((size_t)n * 576 + r * 8 + sh * 4) * HW_ + h * W1_ + w;
        float mv[9][4];
#pragma unroll
        for (int k = 0; k < 9; ++k)
#pragma unroll
            for (int j = 0; j < 4; ++j)
                mv[k][j] = mp[(size_t)(k * 64 + j) * HW_];   // dense in w

        float scale[4];
#pragma unroll
        for (int j = 0; j < 4; ++j) {
            float mx = mv[0][j];
#pragma unroll
            for (int k = 1; k < 9; ++k) mx = fmaxf(mx, mv[k][j]);
            float sum = 0.0f;
#pragma unroll
            for (int k = 0; k < 9; ++k) { mv[k][j] = __expf(mv[k][j] - mx); sum += mv[k][j]; }
            scale[j] = 8.0f / sum;
        }

        const float* __restrict__ f0p = flow + (size_t)n * 2 * HW_;
        const float* __restrict__ f1p = f0p + HW_;
        float a0[4], a1[4];
#pragma unroll
        for (int j = 0; j < 4; ++j) { a0[j] = 0.0f; a1[j] = 0.0f; }

#pragma unroll
        for (int di = 0; di < 3; ++di) {
#pragma unroll
            for (int dj = 0; dj < 3; ++dj) {
                int k = di * 3 + dj;
                int hh = h + di - 1, ww = w + dj - 1;
                bool ok = (hh >= 0) & (hh < H1_) & (ww >= 0) & (ww < W1_);
                float fv0 = ok ? f0p[hh * W1_ + ww] : 0.0f;
                float fv1 = ok ? f1p[hh * W1_ + ww] : 0.0f;
#pragma unroll
                for (int j = 0; j < 4; ++j) {
                    a0[j] += mv[k][j] * fv0;
                    a1[j] += mv[k][j] * fv1;
                }
            }
        }

        float* outU = out + CORR_ELEMS;
        size_t ob = ((size_t)(n * 2 + 0) * (8 * H1_) + h * 8 + r) * (8 * W1_)
                  + (size_t)w * 8 + sh * 4;
        float4 c0 = make_float4(a0[0] * scale[0], a0[1] * scale[1],
                                a0[2] * scale[2], a0[3] * scale[3]);
        float4 c1 = make_float4(a1[0] * scale[0], a1[1] * scale[1],
                                a1[2] * scale[2], a1[3] * scale[3]);
        *(float4*)(outU + ob)         = c0;
        *(float4*)(outU + ob + UP_HW) = c1;
    }
}

extern "C" void kernel_launch(void* const* d_in, const int* in_sizes, int n_in,
                              void* d_out, int out_size, void* d_ws, size_t ws_size,
                              hipStream_t stream) {
    const float* cost   = (const float*)d_in[0];   // [12288, 1, 64, 96]
    const float* coords = (const float*)d_in[1];   // [2, 2, 64, 96]
    const float* flow   = (const float*)d_in[2];   // [2, 2, 64, 96]
    const float* mask   = (const float*)d_in[3];   // [2, 576, 64, 96]
    float* out = (float*)d_out;                    // corr (995328) ++ up_flow (1572864)

    fused_kernel<<<TOT_BLOCKS, 256, 0, stream>>>(cost, coords, flow, mask, out);
}

// Round 7
// 15.396 us; speedup vs baseline: 1.1120x; 1.1120x over previous
//
#include <hip/hip_runtime.h>

// Problem constants (from reference)
#define B_    2
#define H1_   64
#define W1_   96
#define H2_   64
#define W2_   96
#define HW_   (H1_ * W1_)          // 6144, also H2*W2
#define KWIN  81                   // 9x9 lookup window
#define CORR_ELEMS (B_ * KWIN * HW_)              // 995328
#define UP_HW      (8 * H1_ * 8 * W1_)            // 512*768

#define CORR_PIX    (B_ * HW_)                    // 12288 pixels
#define CORR_BLOCKS (CORR_PIX / 64)               // 192 blocks, 64 pixels each
#define UP_THREADS  (B_ * H1_ * 8 * W1_)          // 98304 (n,h,r,w); 8 s per thread
#define UP_BLOCKS   (UP_THREADS / 256)            // 384
#define TOT_BLOCKS  (CORR_BLOCKS + UP_BLOCKS)     // 576

#define PSTRIDE 101                               // LDS stride per pixel (coprime w/ 32)

typedef float float4n __attribute__((ext_vector_type(4)));   // native vec for nontemporal

// ---------------------------------------------------------------------------
// Fused kernel, 256-thread blocks (round-4 structure + non-temporal hints).
//  blocks [0, CORR_BLOCKS): corr — 64 pixels/block, LDS-staged two-phase
//  blocks [CORR_BLOCKS, TOT_BLOCKS): convex upsample — thread per (n,h,r,w)
// Streams cost/mask are read-once -> nontemporal loads; out is write-once ->
// nontemporal stores. coords/flow have heavy reuse -> normal cached loads.
// ---------------------------------------------------------------------------
__global__ __launch_bounds__(256) void fused_kernel(const float* __restrict__ cost,
                                                    const float* __restrict__ coords,
                                                    const float* __restrict__ flow,
                                                    const float* __restrict__ mask,
                                                    float* __restrict__ out) {
    __shared__ float patch[64 * PSTRIDE];          // 25.9 KB
    __shared__ int   xi0s[64];
    __shared__ int   yi0s[64];

    if (blockIdx.x < CORR_BLOCKS) {
        // ---------------- corr ----------------
        int tid  = threadIdx.x;
        int lane = tid & 63;
        int g    = tid >> 6;                        // wave id, 0..3
        int m    = blockIdx.x * 64 + lane;          // this lane's pixel (phase 0/2)
        int b    = m / HW_;                         // uniform per block
        int rem  = m - b * HW_;

        // phase 0: per-pixel params (all 4 waves compute the same, lane=px)
        float cx = coords[b * 2 * HW_ + rem];
        float cy = coords[b * 2 * HW_ + HW_ + rem];
        float xf = floorf(cx), yf = floorf(cy);
        float wx = cx - xf,   wy = cy - yf;
        int xi0 = (int)xf - 4;
        int yi0 = (int)yf - 4;
        float w00 = (1.0f - wx) * (1.0f - wy);
        float w10 = wx * (1.0f - wy);
        float w01 = (1.0f - wx) * wy;
        float w11 = wx * wy;

        if (tid < 64) { xi0s[tid] = xi0; yi0s[tid] = yi0; }
        __syncthreads();

        // phase 1: cooperative patch load — 64 px * 100 elems = 6400 = 25*256
        const float* __restrict__ cmB = cost + (size_t)blockIdx.x * 64 * HW_;
#pragma unroll
        for (int it = 0; it < 25; ++it) {
            unsigned l  = it * 256u + tid;
            unsigned px = l / 100u;
            unsigned e  = l - px * 100u;
            unsigned r  = e / 10u;
            unsigned c  = e - r * 10u;
            int y = yi0s[px] + (int)r;
            int x = xi0s[px] + (int)c;
            bool ok = (x >= 0) & (x < W2_) & (y >= 0) & (y < H2_);
            int yc = min(max(y, 0), H2_ - 1);
            int xc = min(max(x, 0), W2_ - 1);
            float v = __builtin_nontemporal_load(cmB + px * HW_ + yc * W2_ + xc);
            patch[px * PSTRIDE + e] = ok ? v : 0.0f;
        }
        __syncthreads();

        // phase 2: wave g computes contiguous channel chunk; lane = pixel
        const float* __restrict__ pp = patch + lane * PSTRIDE;
        size_t obase = (size_t)b * KWIN * HW_ + rem;
        int start = (g == 0) ? 0 : (1 + 20 * g);    // 0,21,41,61
        int count = (g == 0) ? 21 : 20;
        for (int t = 0; t < count; ++t) {
            int ch = start + t;                      // wave-uniform
            int p  = ch / 9;
            int q  = ch - p * 9;
            int o  = q * 10 + p;
            float val = w00 * pp[o]      + w10 * pp[o + 1]
                      + w01 * pp[o + 10] + w11 * pp[o + 11];
            __builtin_nontemporal_store(val, out + obase + (size_t)ch * HW_);
        }
    } else {
        // ---------------- convex upsample ----------------
        int t = (blockIdx.x - CORR_BLOCKS) * 256 + threadIdx.x;  // [0, 98304)
        int w = t % W1_;
        int u = t / W1_;
        int r = u % 8; u /= 8;
        int h = u % H1_;
        int n = u / H1_;

        // mask: [B, 576, H1, W1]; channel = k*64 + r*8 + s
        const float* __restrict__ mp = mask + ((size_t)n * 576 + r * 8) * HW_ + h * W1_ + w;
        float mv[9][8];
#pragma unroll
        for (int k = 0; k < 9; ++k)
#pragma unroll
            for (int s = 0; s < 8; ++s)
                mv[k][s] = __builtin_nontemporal_load(mp + (size_t)(k * 64 + s) * HW_);

        float scale[8];
#pragma unroll
        for (int s = 0; s < 8; ++s) {
            float mx = mv[0][s];
#pragma unroll
            for (int k = 1; k < 9; ++k) mx = fmaxf(mx, mv[k][s]);
            float sum = 0.0f;
#pragma unroll
            for (int k = 0; k < 9; ++k) { mv[k][s] = __expf(mv[k][s] - mx); sum += mv[k][s]; }
            scale[s] = 8.0f / sum;
        }

        const float* __restrict__ f0p = flow + (size_t)n * 2 * HW_;
        const float* __restrict__ f1p = f0p + HW_;
        float a0[8], a1[8];
#pragma unroll
        for (int s = 0; s < 8; ++s) { a0[s] = 0.0f; a1[s] = 0.0f; }

#pragma unroll
        for (int di = 0; di < 3; ++di) {
#pragma unroll
            for (int dj = 0; dj < 3; ++dj) {
                int k = di * 3 + dj;
                int hh = h + di - 1, ww = w + dj - 1;
                bool ok = (hh >= 0) & (hh < H1_) & (ww >= 0) & (ww < W1_);
                float fv0 = ok ? f0p[hh * W1_ + ww] : 0.0f;
                float fv1 = ok ? f1p[hh * W1_ + ww] : 0.0f;
#pragma unroll
                for (int s = 0; s < 8; ++s) {
                    a0[s] += mv[k][s] * fv0;
                    a1[s] += mv[k][s] * fv1;
                }
            }
        }

        float* outU = out + CORR_ELEMS;
        size_t ob = ((size_t)(n * 2 + 0) * (8 * H1_) + h * 8 + r) * (8 * W1_) + (size_t)w * 8;
        float4n c0a = { a0[0] * scale[0], a0[1] * scale[1], a0[2] * scale[2], a0[3] * scale[3] };
        float4n c0b = { a0[4] * scale[4], a0[5] * scale[5], a0[6] * scale[6], a0[7] * scale[7] };
        float4n c1a = { a1[0] * scale[0], a1[1] * scale[1], a1[2] * scale[2], a1[3] * scale[3] };
        float4n c1b = { a1[4] * scale[4], a1[5] * scale[5], a1[6] * scale[6], a1[7] * scale[7] };
        __builtin_nontemporal_store(c0a, (float4n*)(outU + ob));
        __builtin_nontemporal_store(c0b, (float4n*)(outU + ob + 4));
        __builtin_nontemporal_store(c1a, (float4n*)(outU + ob + UP_HW));
        __builtin_nontemporal_store(c1b, (float4n*)(outU + ob + UP_HW + 4));
    }
}

extern "C" void kernel_launch(void* const* d_in, const int* in_sizes, int n_in,
                              void* d_out, int out_size, void* d_ws, size_t ws_size,
                              hipStream_t stream) {
    const float* cost   = (const float*)d_in[0];   // [12288, 1, 64, 96]
    const float* coords = (const float*)d_in[1];   // [2, 2, 64, 96]
    const float* flow   = (const float*)d_in[2];   // [2, 2, 64, 96]
    const float* mask   = (const float*)d_in[3];   // [2, 576, 64, 96]
    float* out = (float*)d_out;                    // corr (995328) ++ up_flow (1572864)

    fused_kernel<<<TOT_BLOCKS, 256, 0, stream>>>(cost, coords, flow, mask, out);
}

// Round 8
// 14.519 us; speedup vs baseline: 1.1791x; 1.0604x over previous
//
#include <hip/hip_runtime.h>

// Problem constants (from reference)
#define B_    2
#define H1_   64
#define W1_   96
#define H2_   64
#define W2_   96
#define HW_   (H1_ * W1_)          // 6144, also H2*W2
#define KWIN  81                   // 9x9 lookup window
#define CORR_ELEMS (B_ * KWIN * HW_)              // 995328
#define UP_HW      (8 * H1_ * 8 * W1_)            // 512*768

#define CORR_PIX    (B_ * HW_)                    // 12288 pixels
#define CORR_BLOCKS (CORR_PIX / 64)               // 192 blocks, 64 pixels each
#define UP_BLOCKS   (B_ * 8 * 16)                 // 256 blocks: (n, r, h-tile of 4)
#define TOT_BLOCKS  (CORR_BLOCKS + UP_BLOCKS)     // 448, 384-thread blocks

#define PSTRIDE 101                               // LDS stride per pixel (coprime w/ 32)

typedef float float4n __attribute__((ext_vector_type(4)));   // native vec for nontemporal

// ---------------------------------------------------------------------------
// Fused kernel, 384-thread blocks.
//  blocks [0, 192): corr — 64 pixels/block, LDS-staged two-phase (6 waves)
//  blocks [192, 448): convex upsample — block = (n, r, 4-row h-tile);
//      thread (w, hh) does all 8 s + both channels. Block's per-channel mask
//      read = 4 adjacent rows = 1536 B contiguous (vs 256 B before) to raise
//      DRAM burst efficiency on the dominant 28 MB mask stream.
// Streams cost/mask read-once -> nontemporal loads; out write-once ->
// nontemporal stores. coords/flow reused -> normal cached loads.
// ---------------------------------------------------------------------------
__global__ __launch_bounds__(384) void fused_kernel(const float* __restrict__ cost,
                                                    const float* __restrict__ coords,
                                                    const float* __restrict__ flow,
                                                    const float* __restrict__ mask,
                                                    float* __restrict__ out) {
    __shared__ float patch[64 * PSTRIDE];          // 25.9 KB
    __shared__ int   xi0s[64];
    __shared__ int   yi0s[64];

    if (blockIdx.x < CORR_BLOCKS) {
        // ---------------- corr ----------------
        int tid  = threadIdx.x;
        int lane = tid & 63;
        int g    = tid >> 6;                        // wave id, 0..5
        int m    = blockIdx.x * 64 + lane;          // this lane's pixel (phase 0/2)
        int b    = m / HW_;                         // uniform per block
        int rem  = m - b * HW_;

        // phase 0: per-pixel params (all 6 waves compute the same, lane=px)
        float cx = coords[b * 2 * HW_ + rem];
        float cy = coords[b * 2 * HW_ + HW_ + rem];
        float xf = floorf(cx), yf = floorf(cy);
        float wx = cx - xf,   wy = cy - yf;
        int xi0 = (int)xf - 4;
        int yi0 = (int)yf - 4;
        float w00 = (1.0f - wx) * (1.0f - wy);
        float w10 = wx * (1.0f - wy);
        float w01 = (1.0f - wx) * wy;
        float w11 = wx * wy;

        if (tid < 64) { xi0s[tid] = xi0; yi0s[tid] = yi0; }
        __syncthreads();

        // phase 1: cooperative patch load — 64 px * 100 elems = 6400
        const float* __restrict__ cmB = cost + (size_t)blockIdx.x * 64 * HW_;
#pragma unroll
        for (int it = 0; it < 17; ++it) {
            int l = it * 384 + tid;
            if (l < 6400) {
                unsigned px = (unsigned)l / 100u;
                unsigned e  = (unsigned)l - px * 100u;
                unsigned r  = e / 10u;
                unsigned c  = e - r * 10u;
                int y = yi0s[px] + (int)r;
                int x = xi0s[px] + (int)c;
                bool ok = (x >= 0) & (x < W2_) & (y >= 0) & (y < H2_);
                int yc = min(max(y, 0), H2_ - 1);
                int xc = min(max(x, 0), W2_ - 1);
                float v = __builtin_nontemporal_load(cmB + px * HW_ + yc * W2_ + xc);
                patch[px * PSTRIDE + e] = ok ? v : 0.0f;
            }
        }
        __syncthreads();

        // phase 2: wave g computes contiguous channel chunk; lane = pixel
        const float* __restrict__ pp = patch + lane * PSTRIDE;
        size_t obase = (size_t)b * KWIN * HW_ + rem;
        int start = (g < 3) ? 14 * g : 42 + 13 * (g - 3);   // 0,14,28,42,55,68
        int count = (g < 3) ? 14 : 13;
        for (int t = 0; t < count; ++t) {
            int ch = start + t;                      // wave-uniform
            int p  = ch / 9;
            int q  = ch - p * 9;
            int o  = q * 10 + p;
            float val = w00 * pp[o]      + w10 * pp[o + 1]
                      + w01 * pp[o + 10] + w11 * pp[o + 11];
            __builtin_nontemporal_store(val, out + obase + (size_t)ch * HW_);
        }
    } else {
        // ---------------- convex upsample ----------------
        int uid = blockIdx.x - CORR_BLOCKS;          // [0, 256)
        int ht = uid & 15;                           // h-tile (4 rows)
        int r  = (uid >> 4) & 7;
        int n  = uid >> 7;
        int w  = threadIdx.x % 96;
        int hh = threadIdx.x / 96;                   // 0..3
        int h  = ht * 4 + hh;

        // mask: [B, 576, H1, W1]; channel = k*64 + r*8 + s
        const float* __restrict__ mp = mask + ((size_t)n * 576 + r * 8) * HW_ + h * W1_ + w;
        float mv[9][8];
#pragma unroll
        for (int k = 0; k < 9; ++k)
#pragma unroll
            for (int s = 0; s < 8; ++s)
                mv[k][s] = __builtin_nontemporal_load(mp + (size_t)(k * 64 + s) * HW_);

        float scale[8];
#pragma unroll
        for (int s = 0; s < 8; ++s) {
            float mx = mv[0][s];
#pragma unroll
            for (int k = 1; k < 9; ++k) mx = fmaxf(mx, mv[k][s]);
            float sum = 0.0f;
#pragma unroll
            for (int k = 0; k < 9; ++k) { mv[k][s] = __expf(mv[k][s] - mx); sum += mv[k][s]; }
            scale[s] = 8.0f / sum;
        }

        const float* __restrict__ f0p = flow + (size_t)n * 2 * HW_;
        const float* __restrict__ f1p = f0p + HW_;
        float a0[8], a1[8];
#pragma unroll
        for (int s = 0; s < 8; ++s) { a0[s] = 0.0f; a1[s] = 0.0f; }

#pragma unroll
        for (int di = 0; di < 3; ++di) {
#pragma unroll
            for (int dj = 0; dj < 3; ++dj) {
                int k = di * 3 + dj;
                int hx = h + di - 1, wwp = w + dj - 1;
                bool ok = (hx >= 0) & (hx < H1_) & (wwp >= 0) & (wwp < W1_);
                float fv0 = ok ? f0p[hx * W1_ + wwp] : 0.0f;
                float fv1 = ok ? f1p[hx * W1_ + wwp] : 0.0f;
#pragma unroll
                for (int s = 0; s < 8; ++s) {
                    a0[s] += mv[k][s] * fv0;
                    a1[s] += mv[k][s] * fv1;
                }
            }
        }

        float* outU = out + CORR_ELEMS;
        size_t ob = ((size_t)(n * 2 + 0) * (8 * H1_) + h * 8 + r) * (8 * W1_) + (size_t)w * 8;
        float4n c0a = { a0[0] * scale[0], a0[1] * scale[1], a0[2] * scale[2], a0[3] * scale[3] };
        float4n c0b = { a0[4] * scale[4], a0[5] * scale[5], a0[6] * scale[6], a0[7] * scale[7] };
        float4n c1a = { a1[0] * scale[0], a1[1] * scale[1], a1[2] * scale[2], a1[3] * scale[3] };
        float4n c1b = { a1[4] * scale[4], a1[5] * scale[5], a1[6] * scale[6], a1[7] * scale[7] };
        __builtin_nontemporal_store(c0a, (float4n*)(outU + ob));
        __builtin_nontemporal_store(c0b, (float4n*)(outU + ob + 4));
        __builtin_nontemporal_store(c1a, (float4n*)(outU + ob + UP_HW));
        __builtin_nontemporal_store(c1b, (float4n*)(outU + ob + UP_HW + 4));
    }
}

extern "C" void kernel_launch(void* const* d_in, const int* in_sizes, int n_in,
                              void* d_out, int out_size, void* d_ws, size_t ws_size,
                              hipStream_t stream) {
    const float* cost   = (const float*)d_in[0];   // [12288, 1, 64, 96]
    const float* coords = (const float*)d_in[1];   // [2, 2, 64, 96]
    const float* flow   = (const float*)d_in[2];   // [2, 2, 64, 96]
    const float* mask   = (const float*)d_in[3];   // [2, 576, 64, 96]
    float* out = (float*)d_out;                    // corr (995328) ++ up_flow (1572864)

    fused_kernel<<<TOT_BLOCKS, 384, 0, stream>>>(cost, coords, flow, mask, out);
}